// Round 1
// baseline (255.409 us; speedup 1.0000x reference)
//
#include <hip/hip_runtime.h>

typedef unsigned short ushort_t;
typedef __bf16 bf16x8 __attribute__((ext_vector_type(8)));
typedef float f32x16 __attribute__((ext_vector_type(16)));
typedef float f32x4 __attribute__((ext_vector_type(4)));
typedef unsigned int u32x4 __attribute__((ext_vector_type(4)));
typedef unsigned int u32x2 __attribute__((ext_vector_type(2)));

#define L2E 1.44269504088896340736f

__device__ __forceinline__ unsigned cvt_pk_bf16(float a, float b) {
  unsigned r;
  asm("v_cvt_pk_bf16_f32 %0, %1, %2" : "=v"(r) : "v"(a), "v"(b));
  return r;
}

__device__ __forceinline__ float fast_exp2(float v) {
#if __has_builtin(__builtin_amdgcn_exp2f)
  return __builtin_amdgcn_exp2f(v);
#else
  return exp2f(v);
#endif
}

__device__ __forceinline__ f32x16 mfma32(u32x4 a, u32x4 b, f32x16 c) {
  return __builtin_amdgcn_mfma_f32_32x32x16_bf16(
      __builtin_bit_cast(bf16x8, a), __builtin_bit_cast(bf16x8, b), c, 0, 0, 0);
}

// ---------------------------------------------------------------------------
// Projection: [320x256] W @ [256x4096] x  -> Qt[b][n][32], Kt[b][m][32],
// V[b][c][m]  (all bf16).  grid 256 = 8 batches x 32 n-tiles(128).
// LDS: xT [128n][256c] bf16 swizzled (64KB) + W chunk [64o][256c] (32KB).
// ---------------------------------------------------------------------------
__global__ __launch_bounds__(256, 1) void proj_kernel(
    const float* __restrict__ x,
    const float* __restrict__ wq, const float* __restrict__ bq,
    const float* __restrict__ wk, const float* __restrict__ bk,
    const float* __restrict__ wv, const float* __restrict__ bv,
    ushort_t* __restrict__ qtg, ushort_t* __restrict__ ktg,
    ushort_t* __restrict__ vtg)
{
  __shared__ ushort_t xT[128 * 256];
  __shared__ ushort_t wl[64 * 256];

  const int tid  = threadIdx.x;
  const int b    = blockIdx.x & 7;     // batch -> XCD pin
  const int nt   = blockIdx.x >> 3;
  const int n0   = nt * 128;
  const int lane = tid & 63;
  const int wid  = tid >> 6;
  const int l31  = lane & 31;
  const int half = lane >> 5;

  // ---- stage xT[n][c] (bf16, swizzled: byte ^= (n&7)<<4 within row) ----
  {
    const int xn = tid & 127;
    const int ch = (tid >> 7) * 8;
    const float* xb = x + (size_t)b * 256 * 4096 + (n0 + xn);
    #pragma unroll
    for (int rep = 0; rep < 16; ++rep) {
      const int c0 = rep * 16 + ch;
      float f0 = xb[(size_t)(c0+0)*4096], f1 = xb[(size_t)(c0+1)*4096];
      float f2 = xb[(size_t)(c0+2)*4096], f3 = xb[(size_t)(c0+3)*4096];
      float f4 = xb[(size_t)(c0+4)*4096], f5 = xb[(size_t)(c0+5)*4096];
      float f6 = xb[(size_t)(c0+6)*4096], f7 = xb[(size_t)(c0+7)*4096];
      u32x4 pk;
      pk.x = cvt_pk_bf16(f0, f1); pk.y = cvt_pk_bf16(f2, f3);
      pk.z = cvt_pk_bf16(f4, f5); pk.w = cvt_pk_bf16(f6, f7);
      *(u32x4*)((char*)xT + xn*512 + ((c0*2) ^ ((xn & 7) << 4))) = pk;
    }
  }

  for (int oc = 0; oc < 5; ++oc) {
    __syncthreads();  // previous wl reads done (covers xT stage on oc==0)
    // ---- stage W chunk rows [oc*64, oc*64+64) as bf16, swizzled ----
    {
      const int r   = tid >> 2;
      const int row = oc*64 + r;
      const float* wrow = (row < 32) ? (wq + row*256)
                        : (row < 64) ? (wk + (row-32)*256)
                                     : (wv + (row-64)*256);
      #pragma unroll
      for (int rep = 0; rep < 4; ++rep) {
        const int c0 = ((tid & 3)*4 + rep) * 16;
        f32x4 g0 = *(const f32x4*)(wrow + c0);
        f32x4 g1 = *(const f32x4*)(wrow + c0 + 4);
        f32x4 g2 = *(const f32x4*)(wrow + c0 + 8);
        f32x4 g3 = *(const f32x4*)(wrow + c0 + 12);
        u32x4 pa, pb;
        pa.x = cvt_pk_bf16(g0.x, g0.y); pa.y = cvt_pk_bf16(g0.z, g0.w);
        pa.z = cvt_pk_bf16(g1.x, g1.y); pa.w = cvt_pk_bf16(g1.z, g1.w);
        pb.x = cvt_pk_bf16(g2.x, g2.y); pb.y = cvt_pk_bf16(g2.z, g2.w);
        pb.z = cvt_pk_bf16(g3.x, g3.y); pb.w = cvt_pk_bf16(g3.z, g3.w);
        *(u32x4*)((char*)wl + r*512 + ((c0*2)     ^ ((r & 7) << 4))) = pa;
        *(u32x4*)((char*)wl + r*512 + (((c0+8)*2) ^ ((r & 7) << 4))) = pb;
      }
    }
    __syncthreads();

    // ---- per-wave: 32 n-cols x 64 o-rows, K = 256 ----
    f32x16 acc0 = {}, acc1 = {};
    const int nloc = wid*32 + l31;
    #pragma unroll
    for (int kc = 0; kc < 16; ++kc) {
      const int cb = kc*16 + half*8;
      u32x4 bf = *(const u32x4*)((const char*)xT + nloc*512      + ((cb*2) ^ ((nloc & 7) << 4)));
      u32x4 a0 = *(const u32x4*)((const char*)wl + l31*512       + ((cb*2) ^ ((l31  & 7) << 4)));
      u32x4 a1 = *(const u32x4*)((const char*)wl + (32+l31)*512  + ((cb*2) ^ ((l31  & 7) << 4)));
      acc0 = mfma32(a0, bf, acc0);
      acc1 = mfma32(a1, bf, acc1);
    }

    const int nglob = n0 + wid*32 + l31;
    #pragma unroll
    for (int ot = 0; ot < 2; ++ot) {
      f32x16 acc = ot ? acc1 : acc0;
      if (oc == 0) {
        // ot==0 -> Q rows 0..31, ot==1 -> K rows 0..31 ; store [n][o] bf16
        ushort_t* dst = ot ? ktg : qtg;
        const float* bias = ot ? bk : bq;
        const size_t rowbase = ((size_t)b*4096 + nglob) * 32;
        #pragma unroll
        for (int g = 0; g < 4; ++g) {
          const int ob = 8*g + 4*half;        // D row = (r&3)+8*(r>>2)+4*half
          float v0 = acc[4*g+0] + bias[ob+0];
          float v1 = acc[4*g+1] + bias[ob+1];
          float v2 = acc[4*g+2] + bias[ob+2];
          float v3 = acc[4*g+3] + bias[ob+3];
          u32x2 pk2; pk2.x = cvt_pk_bf16(v0, v1); pk2.y = cvt_pk_bf16(v2, v3);
          *(u32x2*)(dst + rowbase + ob) = pk2;
        }
      } else {
        const int cbase = oc*64 - 64 + ot*32;  // V channel base
        #pragma unroll
        for (int r = 0; r < 16; ++r) {
          const int c = cbase + (r & 3) + 8*(r >> 2) + 4*half;
          float v = acc[r] + bv[c];
          vtg[((size_t)b*256 + c)*4096 + nglob] = (ushort_t)cvt_pk_bf16(v, v);
        }
      }
    }
  }
}

// ---------------------------------------------------------------------------
// Flash attention. grid 256 = 8 batches x 32 q-tiles(128); 4 waves x 32 q.
// Swapped QK^T (S^T = K.Q^T) -> lane owns one query column; softmax in-reg.
// V tile (32 keys x 256 ch) double-buffered in LDS via global_load_lds,
// swizzled source / swizzled read (linear dest).  2-phase counted schedule.
// ---------------------------------------------------------------------------
__global__ __launch_bounds__(256, 1) void attn_kernel(
    const ushort_t* __restrict__ qtg, const ushort_t* __restrict__ ktg,
    const ushort_t* __restrict__ vtg, const float* __restrict__ x,
    const float* __restrict__ gamma, float* __restrict__ out)
{
  __shared__ ushort_t vtile[2][8192];  // 2 x 16KB: [c][m] bf16, slot-swizzled

  const int tid  = threadIdx.x;
  const int lane = tid & 63;
  const int wid  = tid >> 6;
  const int l31  = lane & 31;
  const int half = lane >> 5;
  const int b    = blockIdx.x & 7;     // batch -> XCD pin (V stays L2-resident)
  const int qt   = blockIdx.x >> 3;
  const int n0   = qt*128 + wid*32;
  const int nq   = n0 + l31;

  // persistent Q B-fragments (full o-dim = 32 in two K=16 chunks)
  const ushort_t* qrow = qtg + ((size_t)b*4096 + nq)*32;
  const u32x4 q0 = *(const u32x4*)(qrow + half*8);
  const u32x4 q1 = *(const u32x4*)(qrow + 16 + half*8);

  const ushort_t* ktb = ktg + (size_t)b*4096*32;
  const ushort_t* vgb = vtg + (size_t)b*256*4096;

  const int srow = lane >> 2;  // staging: row-within-16
  const int scol = lane & 3;   // staging: 16B slot

  // prologue: stage V tile 0, load K tile 0
  #pragma unroll
  for (int j = 0; j < 4; ++j) {
    const int cr = wid*64 + j*16 + srow;
    const int gs = scol ^ ((cr >> 1) & 3);
    const ushort_t* gp = vgb + (size_t)cr*4096 + gs*8;
    const ushort_t* lp = &vtile[0][0] + (wid*4 + j)*512;
    __builtin_amdgcn_global_load_lds((const __attribute__((address_space(1))) void*)gp,
                                     (__attribute__((address_space(3))) void*)lp, 16, 0, 0);
  }
  u32x4 kf0 = *(const u32x4*)(ktb + (size_t)l31*32 + half*8);
  u32x4 kf1 = *(const u32x4*)(ktb + (size_t)l31*32 + 16 + half*8);
  asm volatile("s_waitcnt vmcnt(0)" ::: "memory");
  __syncthreads();

  float mrun = -3.0e38f, lrun = 0.0f;
  f32x16 oacc[8] = {};
  u32x4 kn0 = q0, kn1 = q1;

  #pragma unroll 2
  for (int t = 0; t < 128; ++t) {
    const int cur = t & 1;
    const char* vb = (const char*)&vtile[0][0] + cur*16384;

    // V fragments for tile t (issue early; swizzled ds_read_b128)
    u32x4 vf0[8], vf1[8];
    #pragma unroll
    for (int ct = 0; ct < 8; ++ct) {
      const int cr = ct*32 + l31;
      const int sw = (cr >> 1) & 3;
      vf0[ct] = *(const u32x4*)(vb + cr*64 + ((half ^ sw) << 4));
      vf1[ct] = *(const u32x4*)(vb + cr*64 + (((2 + half) ^ sw) << 4));
    }

    // prefetch tile t+1: V -> other LDS buffer, K -> regs
    if (t < 127) {
      const int m1 = (t + 1) * 32;
      #pragma unroll
      for (int j = 0; j < 4; ++j) {
        const int cr = wid*64 + j*16 + srow;
        const int gs = scol ^ ((cr >> 1) & 3);
        const ushort_t* gp = vgb + (size_t)cr*4096 + m1 + gs*8;
        const ushort_t* lp = &vtile[0][0] + (cur ^ 1)*8192 + (wid*4 + j)*512;
        __builtin_amdgcn_global_load_lds((const __attribute__((address_space(1))) void*)gp,
                                         (__attribute__((address_space(3))) void*)lp, 16, 0, 0);
      }
      const ushort_t* kr = ktb + (size_t)(m1 + l31)*32;
      kn0 = *(const u32x4*)(kr + half*8);
      kn1 = *(const u32x4*)(kr + 16 + half*8);
    }

    // S^T[m][n] = sum_o Kt[m][o] Qt[n][o]   (32 keys x 32 queries)
    f32x16 s = {};
    s = mfma32(kf0, q0, s);
    s = mfma32(kf1, q1, s);

    // online softmax: lane = query col; 16 m-rows here, 16 in partner lane
    float x0 = fmaxf(s[0],  s[1]),  x1 = fmaxf(s[2],  s[3]);
    float x2 = fmaxf(s[4],  s[5]),  x3 = fmaxf(s[6],  s[7]);
    float x4 = fmaxf(s[8],  s[9]),  x5 = fmaxf(s[10], s[11]);
    float x6 = fmaxf(s[12], s[13]), x7 = fmaxf(s[14], s[15]);
    x0 = fmaxf(x0, x1); x2 = fmaxf(x2, x3);
    x4 = fmaxf(x4, x5); x6 = fmaxf(x6, x7);
    x0 = fmaxf(x0, x2); x4 = fmaxf(x4, x6);
    const float vmx  = fmaxf(x0, x4);
    const float pmax = fmaxf(vmx, __shfl_xor(vmx, 32, 64));

    if (__any(pmax > mrun + 8.0f)) {   // defer-max (T13)
      const float mnew = fmaxf(mrun, pmax);
      const float sc   = fast_exp2((mrun - mnew) * L2E);
      lrun *= sc;
      #pragma unroll
      for (int ct = 0; ct < 8; ++ct)
        #pragma unroll
        for (int r = 0; r < 16; ++r) oacc[ct][r] *= sc;
      mrun = mnew;
    }

    const float ml2 = mrun * L2E;
    float p[16];
    #pragma unroll
    for (int r = 0; r < 16; ++r) p[r] = fast_exp2(fmaf(s[r], L2E, -ml2));
    const float ps = (((p[0]+p[1])+(p[2]+p[3])) + ((p[4]+p[5])+(p[6]+p[7])))
                   + (((p[8]+p[9])+(p[10]+p[11])) + ((p[12]+p[13])+(p[14]+p[15])));
    lrun += ps + __shfl_xor(ps, 32, 64);

    // P^T -> bf16 B-fragments (pack + cross-half exchange)
    const unsigned wd0 = cvt_pk_bf16(p[0],  p[1]),  wd1 = cvt_pk_bf16(p[2],  p[3]);
    const unsigned wd2 = cvt_pk_bf16(p[4],  p[5]),  wd3 = cvt_pk_bf16(p[6],  p[7]);
    const unsigned wd4 = cvt_pk_bf16(p[8],  p[9]),  wd5 = cvt_pk_bf16(p[10], p[11]);
    const unsigned wd6 = cvt_pk_bf16(p[12], p[13]), wd7 = cvt_pk_bf16(p[14], p[15]);
    const unsigned pw0 = __shfl_xor((int)wd0, 32, 64), pw1 = __shfl_xor((int)wd1, 32, 64);
    const unsigned pw2 = __shfl_xor((int)wd2, 32, 64), pw3 = __shfl_xor((int)wd3, 32, 64);
    const unsigned pw4 = __shfl_xor((int)wd4, 32, 64), pw5 = __shfl_xor((int)wd5, 32, 64);
    const unsigned pw6 = __shfl_xor((int)wd6, 32, 64), pw7 = __shfl_xor((int)wd7, 32, 64);
    u32x4 pb0, pb1;
    pb0.x = half ? pw2 : wd0;  pb0.y = half ? pw3 : wd1;
    pb0.z = half ? wd2 : pw0;  pb0.w = half ? wd3 : pw1;
    pb1.x = half ? pw6 : wd4;  pb1.y = half ? pw7 : wd5;
    pb1.z = half ? wd6 : pw4;  pb1.w = half ? wd7 : pw5;

    // O[c][n] += V[c][m] P^T[m][n]
    #pragma unroll
    for (int ct = 0; ct < 8; ++ct) {
      oacc[ct] = mfma32(vf0[ct], pb0, oacc[ct]);
      oacc[ct] = mfma32(vf1[ct], pb1, oacc[ct]);
    }

    asm volatile("s_waitcnt vmcnt(0)" ::: "memory");
    __syncthreads();
    kf0 = kn0; kf1 = kn1;
  }

  // epilogue: out = x + gamma * O / l
  const float inv_l = 1.0f / lrun;
  const float g = gamma[0];
  const size_t xoff = (size_t)b*256*4096 + (size_t)(qt*128 + wid*32 + l31);
  const float* xb = x + xoff;
  float* ob = out + xoff;
  #pragma unroll
  for (int ct = 0; ct < 8; ++ct) {
    #pragma unroll
    for (int r = 0; r < 16; ++r) {
      const int c = ct*32 + (r & 3) + 8*(r >> 2) + 4*half;
      const size_t off = (size_t)c * 4096;
      ob[off] = xb[off] + g * (oacc[ct][r] * inv_l);
    }
  }
}

extern "C" void kernel_launch(void* const* d_in, const int* in_sizes, int n_in,
                              void* d_out, int out_size, void* d_ws, size_t ws_size,
                              hipStream_t stream) {
  (void)in_sizes; (void)n_in; (void)out_size; (void)ws_size;
  const float* x     = (const float*)d_in[0];
  const float* wq    = (const float*)d_in[1];
  const float* bq    = (const float*)d_in[2];
  const float* wk    = (const float*)d_in[3];
  const float* bk    = (const float*)d_in[4];
  const float* wv    = (const float*)d_in[5];
  const float* bv    = (const float*)d_in[6];
  const float* gamma = (const float*)d_in[7];
  float* out = (float*)d_out;

  ushort_t* ws  = (ushort_t*)d_ws;
  ushort_t* qtw = ws;                              // [8][4096][32] bf16
  ushort_t* ktw = ws + (size_t)8*4096*32;          // [8][4096][32] bf16
  ushort_t* vww = ws + (size_t)2*8*4096*32;        // [8][256][4096] bf16

  proj_kernel<<<256, 256, 0, stream>>>(x, wq, bq, wk, bk, wv, bv, qtw, ktw, vww);
  attn_kernel<<<256, 256, 0, stream>>>(qtw, ktw, vww, x, gamma, out);
}